// Round 8
// baseline (213.192 us; speedup 1.0000x reference)
//
#include <hip/hip_runtime.h>

typedef __attribute__((ext_vector_type(8))) short bf16x8;
typedef __attribute__((ext_vector_type(4))) float f32x4;
typedef unsigned short u16;
typedef unsigned int u32;

constexpr int N = 8192;
constexpr int D = 128;
constexpr float CEXP   = 2.8853900817779268f;  // log2(e)/tau, tau = 0.5
constexpr float BSCALE = 1.6986435688113073f;  // sqrt(CEXP) folded into bf16 inputs

#if __has_builtin(__builtin_amdgcn_exp2f)
__device__ __forceinline__ float fexp2(float x) { return __builtin_amdgcn_exp2f(x); }
#else
__device__ __forceinline__ float fexp2(float x) { return exp2f(x); }
#endif

__device__ __forceinline__ u32 f2bf(float x) {
  union { float f; unsigned u; } v;
  v.f = x;
  unsigned r = v.u + 0x7fffu + ((v.u >> 16) & 1u);  // RNE
  return r >> 16;
}

// ---------- fused: fp32->bf16 convert (pre-scaled) + per-row exact dots + zero accums ----------
// one wave per row; lane l handles elements 2l, 2l+1  (verified R5-R7)
__global__ void convert_dots_kernel(const float2* __restrict__ z1, const float2* __restrict__ z2,
                                    u32* __restrict__ o1, u32* __restrict__ o2,
                                    float* __restrict__ dotSelf, float* __restrict__ dotCross,
                                    float* __restrict__ zeroBase, float* __restrict__ out) {
  const int tid = threadIdx.x;
  const int row = blockIdx.x * 4 + (tid >> 6);
  const int l = tid & 63;
  const int zidx = blockIdx.x * 256 + tid;
  if (zidx < 3 * N) zeroBase[zidx] = 0.0f;  // rowRefl | rowBet | colBet
  if (zidx == 0) out[0] = 0.0f;

  float2 a = z1[row * 64 + l];
  float2 b = z2[row * 64 + l];
  o1[row * 64 + l] = f2bf(a.x * BSCALE) | (f2bf(a.y * BSCALE) << 16);
  o2[row * 64 + l] = f2bf(b.x * BSCALE) | (f2bf(b.y * BSCALE) << 16);

  float d11 = a.x * a.x + a.y * a.y;  // |z1_i|^2 partial
  float d12 = a.x * b.x + a.y * b.y;  // z1_i . z2_i partial
#pragma unroll
  for (int mask = 1; mask < 64; mask <<= 1) {
    d11 += __shfl_xor(d11, mask);
    d12 += __shfl_xor(d12, mask);
  }
  if (l == 0) {
    dotSelf[row] = d11;
    dotCross[row] = d12;
  }
}

// ---------- async stage 16KB (64 rows x 256B): linear LDS dest, pre-swizzled src ----------
// swizzled layout: logical (row, chunk c) lives at byte row*256 + ((c ^ (row&15))<<4)  (verified R2/R6/R7)
__device__ __forceinline__ void stage16k(char* lds, const char* gsrc, int soff, int doff) {
#pragma unroll
  for (int s = 0; s < 4; ++s) {
    __builtin_amdgcn_global_load_lds(
        (const __attribute__((address_space(1))) u32*)(gsrc + soff + s * 4096),
        (__attribute__((address_space(3))) u32*)(lds + doff + s * 4096), 16, 0, 0);
  }
}

// ---------- fused GEMM + exp + row/col sums; B from L2 with REGISTER-PREFETCH double buffer ----
// grid: 2048 = bi(128: 64 A-rows) x jg(16). jg<8: refl (B=z1 -> rowRefl);
// jg>=8: between (B=z2 -> rowBet+colBet). Wave w: cols (jg&7)*1024 + g*64 + w*16, g=0..15.
// g-loop unrolled by 2 with NAMED fragment sets (no runtime-indexed arrays -> stays in regs);
// strip g+1's loads issue before computing strip g => L2 latency hides under MFMA+exp.
// launch_bounds(256,3): ~170-reg budget fits af(64)+2x bfr(32)+acc+rowp without spill.
__global__ __launch_bounds__(256, 3) void gemm_kernel(const u16* __restrict__ z1b,
                                                      const u16* __restrict__ z2b,
                                                      float* __restrict__ rowRefl,
                                                      float* __restrict__ rowBet,
                                                      float* __restrict__ colBet) {
  __shared__ __align__(16) char B0[16384];
  const int tid = threadIdx.x;
  const int l = tid & 63, w = tid >> 6;
  const int lr = l & 15, lg = l >> 4;
  const int bi = blockIdx.x >> 4;
  const int jg = blockIdx.x & 15;
  const bool between = jg >= 8;
  const u16* bsrc = between ? z2b : z1b;
  const int col0 = (jg & 7) * 1024 + w * 16;  // this wave's first col (step 64 per g)

  // staging offsets: linear LDS dest, inverse-swizzled global src
  const int soff = (tid >> 4) * 256 + (((tid & 15) ^ (tid >> 4)) << 4);
  const int doff = tid * 16;

  // ---- stage A (rows bi*64..+63) into LDS, read to registers through the swizzle ----
  stage16k(B0, (const char*)(z1b + (size_t)bi * 64 * D), soff, doff);
  __syncthreads();
  bf16x8 af[4][4];  // [m][kk]: row = bi*64 + m*16 + lr, k = kk*32 + lg*8
#pragma unroll
  for (int m = 0; m < 4; ++m)
#pragma unroll
    for (int kk = 0; kk < 4; ++kk)
      af[m][kk] = *(const bf16x8*)(B0 + (m * 16 + lr) * 256 + (((kk * 4 + lg) ^ lr) << 4));
  __syncthreads();  // all waves done reading A
  // clobber the buffer: aliasing store prevents rematerialization of the af loads
  *(u32*)(B0 + ((tid * 64) & 16383)) = 0u;

  float rowp[4][4];
#pragma unroll
  for (int m = 0; m < 4; ++m)
#pragma unroll
    for (int r = 0; r < 4; ++r) rowp[m][r] = 0.f;

  // per-lane B offset within a 16-col group: col-row lr, k-chunk lg; strip stride 16384B
  const char* bbase = (const char*)bsrc + (size_t)(col0 + lr) * 256 + lg * 16;

  // compute one strip given its 4 B fragments (by value => fresh regs per call site)
  auto compute = [&](bf16x8 b0, bf16x8 b1, bf16x8 b2, bf16x8 b3, int g) {
    f32x4 acc[4];
    const f32x4 z4 = {0.f, 0.f, 0.f, 0.f};
#pragma unroll
    for (int m = 0; m < 4; ++m)
      acc[m] = __builtin_amdgcn_mfma_f32_16x16x32_bf16(af[m][0], b0, z4, 0, 0, 0);
#pragma unroll
    for (int m = 0; m < 4; ++m)
      acc[m] = __builtin_amdgcn_mfma_f32_16x16x32_bf16(af[m][1], b1, acc[m], 0, 0, 0);
#pragma unroll
    for (int m = 0; m < 4; ++m)
      acc[m] = __builtin_amdgcn_mfma_f32_16x16x32_bf16(af[m][2], b2, acc[m], 0, 0, 0);
#pragma unroll
    for (int m = 0; m < 4; ++m)
      acc[m] = __builtin_amdgcn_mfma_f32_16x16x32_bf16(af[m][3], b3, acc[m], 0, 0, 0);

    // exp + accumulate. C/D layout: col = lane&15, row (within m-frag) = lg*4 + r.
    if (!between) {
#pragma unroll
      for (int m = 0; m < 4; ++m)
#pragma unroll
        for (int r = 0; r < 4; ++r) rowp[m][r] += fexp2(acc[m][r]);
    } else {
      float colp = 0.f;
#pragma unroll
      for (int m = 0; m < 4; ++m) {
        float v0 = fexp2(acc[m][0]), v1 = fexp2(acc[m][1]);
        float v2 = fexp2(acc[m][2]), v3 = fexp2(acc[m][3]);
        rowp[m][0] += v0;
        rowp[m][1] += v1;
        rowp[m][2] += v2;
        rowp[m][3] += v3;
        colp += (v0 + v1) + (v2 + v3);
      }
      colp += __shfl_xor(colp, 16);
      colp += __shfl_xor(colp, 32);
      if (l < 16) atomicAdd(&colBet[col0 + g * 64 + l], colp);
    }
  };

#define LOADB(d0, d1, d2, d3, p)              \
  d0 = *(const bf16x8*)(p);                   \
  d1 = *(const bf16x8*)((p) + 64);            \
  d2 = *(const bf16x8*)((p) + 128);           \
  d3 = *(const bf16x8*)((p) + 192)

  bf16x8 a0, a1, a2, a3, c0, c1, c2, c3;
  LOADB(a0, a1, a2, a3, bbase);  // prologue: strip 0
#pragma unroll
  for (int g = 0; g < 16; g += 2) {
    LOADB(c0, c1, c2, c3, bbase + (size_t)(g + 1) * 16384);  // prefetch strip g+1
    compute(a0, a1, a2, a3, g);
    if (g + 2 < 16) {
      LOADB(a0, a1, a2, a3, bbase + (size_t)(g + 2) * 16384);  // prefetch strip g+2
    }
    compute(c0, c1, c2, c3, g + 1);
  }
#undef LOADB

  // ---- deferred row reduction: shuffle over the 16 col-lanes, one atomic per row ----
  float* rowdst = between ? rowBet : rowRefl;
#pragma unroll
  for (int m = 0; m < 4; ++m)
#pragma unroll
    for (int r = 0; r < 4; ++r) {
      float s = rowp[m][r];
      s += __shfl_xor(s, 1);
      s += __shfl_xor(s, 2);
      s += __shfl_xor(s, 4);
      s += __shfl_xor(s, 8);
      if (lr == 0) atomicAdd(&rowdst[bi * 64 + m * 16 + lg * 4 + r], s);
    }
}

// ---------- per-row loss (exact fp32 diagonals) + mean  (verified R5-R7) ----------
__global__ void final_kernel(const float* __restrict__ rowRefl, const float* __restrict__ rowBet,
                             const float* __restrict__ colBet, const float* __restrict__ dotSelf,
                             const float* __restrict__ dotCross, float* __restrict__ out) {
  const int r = blockIdx.x * 256 + threadIdx.x;  // 32 blocks x 256 = 8192
  float rdiag = fexp2(dotSelf[r] * CEXP);        // exp(|z1_i|^2/tau), exact fp32
  float base = rowRefl[r] - rdiag;
  // -log(pos) = -d12/tau = -2*d12 exactly (no exp/log roundtrip)
  float loss = 0.5f * (logf(base + rowBet[r]) + logf(base + colBet[r])) - 2.0f * dotCross[r];
  loss *= (1.0f / (float)N);
#pragma unroll
  for (int mask = 1; mask < 64; mask <<= 1) loss += __shfl_xor(loss, mask);
  if ((threadIdx.x & 63) == 0) atomicAdd(out, loss);
}

extern "C" void kernel_launch(void* const* d_in, const int* in_sizes, int n_in,
                              void* d_out, int out_size, void* d_ws, size_t ws_size,
                              hipStream_t stream) {
  const float* z1 = (const float*)d_in[0];
  const float* z2 = (const float*)d_in[1];
  float* out = (float*)d_out;
  char* ws = (char*)d_ws;

  // ws: z1b(2MB) | z2b(2MB) | rowRefl(N) | rowBet(N) | colBet(N) | dotSelf(N) | dotCross(N)
  u16* z1b = (u16*)ws;
  u16* z2b = (u16*)(ws + (size_t)N * D * 2);
  float* rowRefl = (float*)(ws + (size_t)2 * N * D * 2);
  float* rowBet = rowRefl + N;
  float* colBet = rowBet + N;
  float* dotSelf = colBet + N;
  float* dotCross = dotSelf + N;

  convert_dots_kernel<<<N / 4, 256, 0, stream>>>((const float2*)z1, (const float2*)z2,
                                                 (u32*)z1b, (u32*)z2b, dotSelf, dotCross,
                                                 rowRefl, out);
  gemm_kernel<<<2048, 256, 0, stream>>>(z1b, z2b, rowRefl, rowBet, colBet);
  final_kernel<<<N / 256, 256, 0, stream>>>(rowRefl, rowBet, colBet, dotSelf, dotCross, out);
}

// Round 9
// 71.724 us; speedup vs baseline: 2.9724x; 2.9724x over previous
//
#include <hip/hip_runtime.h>

typedef __attribute__((ext_vector_type(8))) short bf16x8;
typedef __attribute__((ext_vector_type(4))) float f32x4;
typedef unsigned short u16;
typedef unsigned int u32;

constexpr int N = 8192;
constexpr int D = 128;
constexpr float CEXP   = 2.8853900817779268f;  // log2(e)/tau, tau = 0.5
constexpr float BSCALE = 1.6986435688113073f;  // sqrt(CEXP) folded into bf16 inputs

#if __has_builtin(__builtin_amdgcn_exp2f)
__device__ __forceinline__ float fexp2(float x) { return __builtin_amdgcn_exp2f(x); }
#else
__device__ __forceinline__ float fexp2(float x) { return exp2f(x); }
#endif

__device__ __forceinline__ u32 f2bf(float x) {
  union { float f; unsigned u; } v;
  v.f = x;
  unsigned r = v.u + 0x7fffu + ((v.u >> 16) & 1u);  // RNE
  return r >> 16;
}

// ---------- fused: fp32->bf16 convert (pre-scaled) + per-row exact dots + zero accums ----------
__global__ void convert_dots_kernel(const float2* __restrict__ z1, const float2* __restrict__ z2,
                                    u32* __restrict__ o1, u32* __restrict__ o2,
                                    float* __restrict__ dotSelf, float* __restrict__ dotCross,
                                    float* __restrict__ zeroBase, float* __restrict__ out) {
  const int tid = threadIdx.x;
  const int row = blockIdx.x * 4 + (tid >> 6);
  const int l = tid & 63;
  const int zidx = blockIdx.x * 256 + tid;
  if (zidx < 3 * N) zeroBase[zidx] = 0.0f;  // rowRefl | rowBet | colBet
  if (zidx == 0) out[0] = 0.0f;

  float2 a = z1[row * 64 + l];
  float2 b = z2[row * 64 + l];
  o1[row * 64 + l] = f2bf(a.x * BSCALE) | (f2bf(a.y * BSCALE) << 16);
  o2[row * 64 + l] = f2bf(b.x * BSCALE) | (f2bf(b.y * BSCALE) << 16);

  float d11 = a.x * a.x + a.y * a.y;
  float d12 = a.x * b.x + a.y * b.y;
#pragma unroll
  for (int mask = 1; mask < 64; mask <<= 1) {
    d11 += __shfl_xor(d11, mask);
    d12 += __shfl_xor(d12, mask);
  }
  if (l == 0) {
    dotSelf[row] = d11;
    dotCross[row] = d12;
  }
}

// ---------- wave-private async stage: 4KB panel (16 cols x 256B), linear LDS, pre-swizzled src ----
// LDS (r, c) holds global (r, c ^ r); r = s*4 + (l>>4), c = l&15, 16B chunks.
__device__ __forceinline__ void stageB(char* ldsbase, const char* gpanel, int l) {
#pragma unroll
  for (int s = 0; s < 4; ++s) {
    const int r = s * 4 + (l >> 4);
    const int src = r * 256 + (((l & 15) ^ r) << 4);
    __builtin_amdgcn_global_load_lds(
        (const __attribute__((address_space(1))) u32*)(gpanel + src),
        (__attribute__((address_space(3))) u32*)(ldsbase + s * 1024 + l * 16), 16, 0, 0);
  }
}

// ---------- fused GEMM + exp + row/col sums; wave-private LDS dbuf, ZERO hot-loop barriers ----
// grid: 2048 = bi(128: 64 A-rows) x jg(16). jg<8: refl (B=z1 -> rowRefl);
// jg>=8: between (B=z2 -> rowBet+colBet). Wave w: cols (jg&7)*1024 + w*16 + t*64, t=0..15.
// Per strip: stage(t+1) -> s_waitcnt vmcnt(4) (counted, never 0: T4) -> ds_read(t) -> MFMA -> exp.
// Col partials deferred via wave-private LDS so NO vmem ops pollute the vmcnt count.
__global__ __launch_bounds__(256, 3) void gemm_kernel(const u16* __restrict__ z1b,
                                                      const u16* __restrict__ z2b,
                                                      float* __restrict__ rowRefl,
                                                      float* __restrict__ rowBet,
                                                      float* __restrict__ colBet) {
  __shared__ __align__(16) char Bbuf[32768];   // A-stage (first 16KB) then 4 waves x 2 x 4KB
  __shared__ float colLds[4][256];             // per-wave deferred col partials (16 strips x 16)
  const int tid = threadIdx.x;
  const int l = tid & 63, w = tid >> 6;
  const int lr = l & 15, lg = l >> 4;
  const int bi = blockIdx.x >> 4;
  const int jg = blockIdx.x & 15;
  const bool between = jg >= 8;
  const u16* bsrc = between ? z2b : z1b;
  const int colbase = (jg & 7) * 1024;

  // ---- A prologue: stage 16KB (rows bi*64..+63) into Bbuf[0:16K], read af through swizzle ----
  {
    const int soff = (tid >> 4) * 256 + (((tid & 15) ^ (tid >> 4)) << 4);
    const char* gA = (const char*)(z1b + (size_t)bi * 64 * D);
#pragma unroll
    for (int s = 0; s < 4; ++s) {
      __builtin_amdgcn_global_load_lds(
          (const __attribute__((address_space(1))) u32*)(gA + soff + s * 4096),
          (__attribute__((address_space(3))) u32*)(Bbuf + tid * 16 + s * 4096), 16, 0, 0);
    }
  }
  __syncthreads();
  bf16x8 af[4][4];  // [m][kk]: row = bi*64 + m*16 + lr, k = kk*32 + lg*8
#pragma unroll
  for (int m = 0; m < 4; ++m)
#pragma unroll
    for (int kk = 0; kk < 4; ++kk)
      af[m][kk] = *(const bf16x8*)(Bbuf + (m * 16 + lr) * 256 + (((kk * 4 + lg) ^ lr) << 4));
  __syncthreads();  // all waves done reading A; Bbuf now free for wave-private buffers
  asm volatile("" ::: "memory");  // no load motion across this point

  char* myBuf = Bbuf + w * 8192;  // two 4KB halves, this wave only
  const char* gB = (const char*)bsrc + (size_t)(colbase + w * 16) * 256;  // strip stride 16KB

  float rowp[4][4];
#pragma unroll
  for (int m = 0; m < 4; ++m)
#pragma unroll
    for (int r = 0; r < 4; ++r) rowp[m][r] = 0.f;

  stageB(myBuf, gB, l);  // prologue: strip 0 -> half 0 (4 outstanding)

  for (int t = 0; t < 16; ++t) {
    const char* cur = myBuf + (t & 1) * 4096;
    if (t < 15) {
      stageB(myBuf + ((t + 1) & 1) * 4096, gB + (size_t)(t + 1) * 16384, l);
      asm volatile("s_waitcnt vmcnt(4)" ::: "memory");  // strip t landed; t+1 stays in flight
    } else {
      asm volatile("s_waitcnt vmcnt(0)" ::: "memory");
    }

    bf16x8 bfr[4];
#pragma unroll
    for (int kk = 0; kk < 4; ++kk)
      bfr[kk] = *(const bf16x8*)(cur + lr * 256 + (((kk * 4 + lg) ^ lr) << 4));

    f32x4 acc[4];
    const f32x4 z4 = {0.f, 0.f, 0.f, 0.f};
#pragma unroll
    for (int m = 0; m < 4; ++m)
      acc[m] = __builtin_amdgcn_mfma_f32_16x16x32_bf16(af[m][0], bfr[0], z4, 0, 0, 0);
#pragma unroll
    for (int kk = 1; kk < 4; ++kk)
#pragma unroll
      for (int m = 0; m < 4; ++m)
        acc[m] = __builtin_amdgcn_mfma_f32_16x16x32_bf16(af[m][kk], bfr[kk], acc[m], 0, 0, 0);

    // exp + accumulate. C/D layout: col = lane&15, row (within m-frag) = lg*4 + r.
    if (!between) {
#pragma unroll
      for (int m = 0; m < 4; ++m)
#pragma unroll
        for (int r = 0; r < 4; ++r) rowp[m][r] += fexp2(acc[m][r]);
    } else {
      float colp = 0.f;
#pragma unroll
      for (int m = 0; m < 4; ++m) {
        float v0 = fexp2(acc[m][0]), v1 = fexp2(acc[m][1]);
        float v2 = fexp2(acc[m][2]), v3 = fexp2(acc[m][3]);
        rowp[m][0] += v0;
        rowp[m][1] += v1;
        rowp[m][2] += v2;
        rowp[m][3] += v3;
        colp += (v0 + v1) + (v2 + v3);
      }
      colp += __shfl_xor(colp, 16);
      colp += __shfl_xor(colp, 32);
      if (l < 16) colLds[w][t * 16 + l] = colp;  // defer: keep vmcnt stream pure
    }
  }

  // ---- deferred col atomics (once per block) ----
  if (between && l < 16) {
#pragma unroll
    for (int t = 0; t < 16; ++t)
      atomicAdd(&colBet[colbase + t * 64 + w * 16 + l], colLds[w][t * 16 + l]);
  }

  // ---- deferred row reduction: shuffle over the 16 col-lanes, one atomic per row ----
  float* rowdst = between ? rowBet : rowRefl;
#pragma unroll
  for (int m = 0; m < 4; ++m)
#pragma unroll
    for (int r = 0; r < 4; ++r) {
      float s = rowp[m][r];
      s += __shfl_xor(s, 1);
      s += __shfl_xor(s, 2);
      s += __shfl_xor(s, 4);
      s += __shfl_xor(s, 8);
      if (lr == 0) atomicAdd(&rowdst[bi * 64 + m * 16 + lg * 4 + r], s);
    }
}

// ---------- per-row loss (exact fp32 diagonals) + mean ----------
__global__ void final_kernel(const float* __restrict__ rowRefl, const float* __restrict__ rowBet,
                             const float* __restrict__ colBet, const float* __restrict__ dotSelf,
                             const float* __restrict__ dotCross, float* __restrict__ out) {
  const int r = blockIdx.x * 256 + threadIdx.x;
  float rdiag = fexp2(dotSelf[r] * CEXP);
  float base = rowRefl[r] - rdiag;
  float loss = 0.5f * (logf(base + rowBet[r]) + logf(base + colBet[r])) - 2.0f * dotCross[r];
  loss *= (1.0f / (float)N);
#pragma unroll
  for (int mask = 1; mask < 64; mask <<= 1) loss += __shfl_xor(loss, mask);
  if ((threadIdx.x & 63) == 0) atomicAdd(out, loss);
}

extern "C" void kernel_launch(void* const* d_in, const int* in_sizes, int n_in,
                              void* d_out, int out_size, void* d_ws, size_t ws_size,
                              hipStream_t stream) {
  const float* z1 = (const float*)d_in[0];
  const float* z2 = (const float*)d_in[1];
  float* out = (float*)d_out;
  char* ws = (char*)d_ws;

  // ws: z1b(2MB) | z2b(2MB) | rowRefl(N) | rowBet(N) | colBet(N) | dotSelf(N) | dotCross(N)
  u16* z1b = (u16*)ws;
  u16* z2b = (u16*)(ws + (size_t)N * D * 2);
  float* rowRefl = (float*)(ws + (size_t)2 * N * D * 2);
  float* rowBet = rowRefl + N;
  float* colBet = rowBet + N;
  float* dotSelf = colBet + N;
  float* dotCross = dotSelf + N;

  convert_dots_kernel<<<N / 4, 256, 0, stream>>>((const float2*)z1, (const float2*)z2,
                                                 (u32*)z1b, (u32*)z2b, dotSelf, dotCross,
                                                 rowRefl, out);
  gemm_kernel<<<2048, 256, 0, stream>>>(z1b, z2b, rowRefl, rowBet, colBet);
  final_kernel<<<N / 256, 256, 0, stream>>>(rowRefl, rowBet, colBet, dotSelf, dotCross, out);
}